// Round 6
// baseline (4909.665 us; speedup 1.0000x reference)
//
#include <hip/hip_runtime.h>
#include <hip/hip_bf16.h>

// TimeResampler (perceiver resampler w/ timestep conditioning), fp32 baseline.
// R5: fused final reduce+bias+LN (k_redout). Otherwise identical to R4:
// XCD-locality grid swap (SWAP) for ff1/ff2/wo/proj_out; proj_in TM=8;
// fused mlat-LN in k_attn; k_redln; split-K for M=256 GEMMs; normh in-place.
//
// Math restructuring vs reference (exact, fewer FLOPs):
//  * scores:  q_h @ (kv_in@Wk_h)^T  ==  (q_h@Wk_h^T) @ kv_in^T      (U-trick)
//  * PV:      P @ (kv_in@Wv_h)      ==  (P@kv_in) @ Wv_h
//  * LN fold: xn = norm(h)*g1+b1, norm(h) layer-invariant -> computed once;
//             g1 folded into U, b1 into per-row scalar ub + rowsum(P)*b1.
//  * latent K/V rows (8/batch) via tiny per-head klat/vlat projections.

#define NLOG10K -9.210340371976184f

// ---------------- timestep embedding + temb MLP (32 rows, tiny) --------------
__global__ __launch_bounds__(256) void k_temb(
    const int* __restrict__ ts,
    const float* __restrict__ w1, const float* __restrict__ b1,
    const float* __restrict__ w2, const float* __restrict__ b2,
    float* __restrict__ temb, float* __restrict__ st)
{
  int b = blockIdx.x, t = threadIdx.x;
  __shared__ float te[320];
  __shared__ float a1[1024];
  float tv = (float)ts[b];
  for (int j = t; j < 160; j += 256) {
    float arg = tv * expf(NLOG10K * (float)j / 160.f);
    te[j] = cosf(arg);
    te[160 + j] = sinf(arg);
  }
  __syncthreads();
  for (int o = t; o < 1024; o += 256) {
    float acc = b1[o];
    for (int k = 0; k < 320; ++k) acc = fmaf(te[k], w1[k * 1024 + o], acc);
    a1[o] = acc / (1.f + expf(-acc));   // silu
  }
  __syncthreads();
  for (int o = t; o < 1024; o += 256) {
    float acc = b2[o];
    for (int k = 0; k < 1024; ++k) acc = fmaf(a1[k], w2[k * 1024 + o], acc);
    temb[b * 1024 + o] = acc;
    st[b * 1024 + o] = acc / (1.f + expf(-acc));   // silu(temb) for adaLN
  }
}

// ---------------- row LayerNorm over 1024 cols (1 wave per row) --------------
// Safe for X==Y (row fully loaded to registers before writeback).
__global__ __launch_bounds__(256) void k_ln(
    const float* __restrict__ X, float* __restrict__ Y,
    const float* __restrict__ g, const float* __restrict__ bb)
{
  int w = threadIdx.x >> 6, lane = threadIdx.x & 63;
  int row = blockIdx.x * 4 + w;
  const float* x = X + (size_t)row * 1024;
  float4 v[4];
  float s = 0.f;
#pragma unroll
  for (int ch = 0; ch < 4; ++ch) {
    v[ch] = *(const float4*)(x + lane * 4 + ch * 256);
    s += v[ch].x + v[ch].y + v[ch].z + v[ch].w;
  }
#pragma unroll
  for (int off = 32; off; off >>= 1) s += __shfl_xor(s, off);
  float mean = s * (1.f / 1024.f);
  float vs = 0.f;
#pragma unroll
  for (int ch = 0; ch < 4; ++ch) {
    float dx;
    dx = v[ch].x - mean; vs = fmaf(dx, dx, vs);
    dx = v[ch].y - mean; vs = fmaf(dx, dx, vs);
    dx = v[ch].z - mean; vs = fmaf(dx, dx, vs);
    dx = v[ch].w - mean; vs = fmaf(dx, dx, vs);
  }
#pragma unroll
  for (int off = 32; off; off >>= 1) vs += __shfl_xor(vs, off);
  float rstd = rsqrtf(vs * (1.f / 1024.f) + 1e-5f);
  float* y = Y + (size_t)row * 1024;
#pragma unroll
  for (int ch = 0; ch < 4; ++ch) {
    int c = lane * 4 + ch * 256;
    float4 o;
    o.x = (v[ch].x - mean) * rstd;
    o.y = (v[ch].y - mean) * rstd;
    o.z = (v[ch].z - mean) * rstd;
    o.w = (v[ch].w - mean) * rstd;
    if (g) {
      float4 gg = *(const float4*)(g + c);
      float4 bv = *(const float4*)(bb + c);
      o.x = fmaf(o.x, gg.x, bv.x);
      o.y = fmaf(o.y, gg.y, bv.y);
      o.z = fmaf(o.z, gg.z, bv.z);
      o.w = fmaf(o.w, gg.w, bv.w);
    }
    *(float4*)(y + c) = o;
  }
}

// ---------------- latent broadcast init --------------------------------------
__global__ __launch_bounds__(256) void k_latinit(
    const float* __restrict__ lat0, float* __restrict__ lat)
{
  int i = blockIdx.x * 256 + threadIdx.x;          // float4 index, 65536 total
  ((float4*)lat)[i] = ((const float4*)lat0)[i & 2047];
}

// ---------------- generic fp32 GEMM: C = A[M,·] @ B[·,N] (+bias)(+epi) -------
// lda = A row stride; K = contraction length of THIS call (split-K chunk).
// Per-z offsets: A += bz*sA (column offset), B += bz*sB, C += bz*sC.
// epi bit0: exact GELU; bit1: += temb[row/257]; bit2: += res[row,col]
// SWAP: grid is (colTiles, rowTiles) so blocks sharing a B column-tile get
// consecutive flattened ids only in y -> same XCD (id%8 == colTile%8).
template <int TM, bool SWAP = false>
__global__ __launch_bounds__(256, 4) void k_gemm(
    const float* __restrict__ A, long sA, int lda,
    const float* __restrict__ B, long sB,
    float* __restrict__ C, long sC,
    const float* __restrict__ bias, int sBias,
    const float* __restrict__ res,
    const float* __restrict__ temb,
    int M, int N, int K, int epi)
{
  constexpr int BM = 16 * TM;
  constexpr int BK = 32;
  constexpr int LDA = BM + 4;
  __shared__ float aT[BK][LDA];     // transposed A tile
  __shared__ float bT[BK][64];
  int bz = blockIdx.z;
  A += (size_t)bz * sA; B += (size_t)bz * sB; C += (size_t)bz * sC;
  const float* biasp = bias ? bias + (size_t)bz * sBias : nullptr;
  int r0 = (SWAP ? blockIdx.y : blockIdx.x) * BM;
  int c0 = (SWAP ? blockIdx.x : blockIdx.y) * 64;
  int t = threadIdx.x;
  int tx = t & 15, ty = t >> 4;
  float acc[TM][4] = {};
  for (int k0 = 0; k0 < K; k0 += BK) {
#pragma unroll
    for (int f = 0; f < BM / 32; ++f) {
      int lin = t + f * 256;
      int row = lin >> 3, k4 = (lin & 7) << 2;
      float4 v = make_float4(0.f, 0.f, 0.f, 0.f);
      int gr = r0 + row;
      if (gr < M) v = *(const float4*)(A + (size_t)gr * lda + k0 + k4);
      aT[k4][row] = v.x; aT[k4 + 1][row] = v.y;
      aT[k4 + 2][row] = v.z; aT[k4 + 3][row] = v.w;
    }
#pragma unroll
    for (int f = 0; f < 2; ++f) {
      int lin = t + f * 256;
      int kr = lin >> 4, n4 = (lin & 15) << 2;
      *(float4*)(&bT[kr][n4]) = *(const float4*)(B + (size_t)(k0 + kr) * N + c0 + n4);
    }
    __syncthreads();
#pragma unroll
    for (int kk = 0; kk < BK; ++kk) {
      float4 bv = *(const float4*)(&bT[kk][tx * 4]);
      float av[TM];
#pragma unroll
      for (int i = 0; i < TM; ++i) av[i] = aT[kk][ty * TM + i];
#pragma unroll
      for (int i = 0; i < TM; ++i) {
        acc[i][0] = fmaf(av[i], bv.x, acc[i][0]);
        acc[i][1] = fmaf(av[i], bv.y, acc[i][1]);
        acc[i][2] = fmaf(av[i], bv.z, acc[i][2]);
        acc[i][3] = fmaf(av[i], bv.w, acc[i][3]);
      }
    }
    __syncthreads();
  }
#pragma unroll
  for (int i = 0; i < TM; ++i) {
    int gr = r0 + ty * TM + i;
    if (gr >= M) continue;
    int gc = c0 + tx * 4;
    float4 v = make_float4(acc[i][0], acc[i][1], acc[i][2], acc[i][3]);
    if (biasp) {
      float4 bv = *(const float4*)(biasp + gc);
      v.x += bv.x; v.y += bv.y; v.z += bv.z; v.w += bv.w;
    }
    if (epi & 2) {
      float4 tb = *(const float4*)(temb + (size_t)(gr / 257) * 1024 + gc);
      v.x += tb.x; v.y += tb.y; v.z += tb.z; v.w += tb.w;
    }
    if (epi & 1) {
      v.x = 0.5f * v.x * (1.f + erff(v.x * 0.70710678f));
      v.y = 0.5f * v.y * (1.f + erff(v.y * 0.70710678f));
      v.z = 0.5f * v.z * (1.f + erff(v.z * 0.70710678f));
      v.w = 0.5f * v.w * (1.f + erff(v.w * 0.70710678f));
    }
    if (epi & 4) {
      float4 rv = *(const float4*)(res + (size_t)gr * N + gc);
      v.x += rv.x; v.y += rv.y; v.z += rv.z; v.w += rv.w;
    }
    *(float4*)(C + (size_t)gr * N + gc) = v;
  }
}

// ---------------- split-K reduce: out = sum_z part[z] (+res) -----------------
__global__ __launch_bounds__(256) void k_reduce(
    const float* __restrict__ part, int sPart4, int nz,
    const float* __restrict__ res,
    float* __restrict__ out, int total4)
{
  int i = blockIdx.x * 256 + threadIdx.x;
  if (i >= total4) return;
  const float4* p4 = (const float4*)part;
  float4 a = p4[i];
  for (int z = 1; z < nz; ++z) {
    float4 b = p4[i + (size_t)z * sPart4];
    a.x += b.x; a.y += b.y; a.z += b.z; a.w += b.w;
  }
  if (res) {
    float4 r = ((const float4*)res)[i];
    a.x += r.x; a.y += r.y; a.z += r.z; a.w += r.w;
  }
  ((float4*)out)[i] = a;
}

// ------- fused: lat = sum_z pp[z] + lat;  yb = LN(lat;g,b)*(1+scale)+shift ---
// one wave per row (256 rows over 64 blocks)
__global__ __launch_bounds__(256) void k_redln(
    const float* __restrict__ pp, int nz, int sPart4,
    float* __restrict__ lat, float* __restrict__ yb,
    const float* __restrict__ g, const float* __restrict__ bb,
    const float* __restrict__ ada, int shift_off, int scale_off)
{
  int w = threadIdx.x >> 6, lane = threadIdx.x & 63;
  int row = blockIdx.x * 4 + w;
  const float4* p4 = (const float4*)pp;
  float4* lat4 = (float4*)lat;
  size_t base4 = (size_t)row * 256 + lane;
  float4 v[4];
  float s = 0.f;
#pragma unroll
  for (int ch = 0; ch < 4; ++ch) {
    size_t i = base4 + ch * 64;
    float4 a = p4[i];
    for (int z = 1; z < nz; ++z) {
      float4 b = p4[i + (size_t)z * sPart4];
      a.x += b.x; a.y += b.y; a.z += b.z; a.w += b.w;
    }
    float4 r = lat4[i];
    a.x += r.x; a.y += r.y; a.z += r.z; a.w += r.w;
    lat4[i] = a;
    v[ch] = a;
    s += a.x + a.y + a.z + a.w;
  }
#pragma unroll
  for (int off = 32; off; off >>= 1) s += __shfl_xor(s, off);
  float mean = s * (1.f / 1024.f);
  float vs = 0.f;
#pragma unroll
  for (int ch = 0; ch < 4; ++ch) {
    float dx;
    dx = v[ch].x - mean; vs = fmaf(dx, dx, vs);
    dx = v[ch].y - mean; vs = fmaf(dx, dx, vs);
    dx = v[ch].z - mean; vs = fmaf(dx, dx, vs);
    dx = v[ch].w - mean; vs = fmaf(dx, dx, vs);
  }
#pragma unroll
  for (int off = 32; off; off >>= 1) vs += __shfl_xor(vs, off);
  float rstd = rsqrtf(vs * (1.f / 1024.f) + 1e-5f);
  const float* ab = ada + (size_t)(row >> 3) * 4096;
  float* y = yb + (size_t)row * 1024;
#pragma unroll
  for (int ch = 0; ch < 4; ++ch) {
    int c = lane * 4 + ch * 256;
    float4 gg = *(const float4*)(g + c);
    float4 bv = *(const float4*)(bb + c);
    float4 sc = *(const float4*)(ab + scale_off + c);
    float4 sh = *(const float4*)(ab + shift_off + c);
    float4 o;
    o.x = fmaf((v[ch].x - mean) * rstd, gg.x, bv.x);
    o.y = fmaf((v[ch].y - mean) * rstd, gg.y, bv.y);
    o.z = fmaf((v[ch].z - mean) * rstd, gg.z, bv.z);
    o.w = fmaf((v[ch].w - mean) * rstd, gg.w, bv.w);
    o.x = fmaf(o.x, 1.f + sc.x, sh.x);
    o.y = fmaf(o.y, 1.f + sc.y, sh.y);
    o.z = fmaf(o.z, 1.f + sc.z, sh.z);
    o.w = fmaf(o.w, 1.f + sc.w, sh.w);
    *(float4*)(y + c) = o;
  }
}

// ------- fused epilogue: out = LN(sum_z pp[z] + bias; g, b) ------------------
// one wave per row (256 rows over 64 blocks)
__global__ __launch_bounds__(256) void k_redout(
    const float* __restrict__ pp, int nz, int sPart4,
    const float* __restrict__ bias,
    const float* __restrict__ g, const float* __restrict__ bb,
    float* __restrict__ out)
{
  int w = threadIdx.x >> 6, lane = threadIdx.x & 63;
  int row = blockIdx.x * 4 + w;
  const float4* p4 = (const float4*)pp;
  const float4* b4p = (const float4*)bias;
  size_t base4 = (size_t)row * 256 + lane;
  float4 v[4];
  float s = 0.f;
#pragma unroll
  for (int ch = 0; ch < 4; ++ch) {
    size_t i = base4 + ch * 64;
    float4 a = p4[i];
    for (int z = 1; z < nz; ++z) {
      float4 b = p4[i + (size_t)z * sPart4];
      a.x += b.x; a.y += b.y; a.z += b.z; a.w += b.w;
    }
    float4 bv = b4p[lane + ch * 64];
    a.x += bv.x; a.y += bv.y; a.z += bv.z; a.w += bv.w;
    v[ch] = a;
    s += a.x + a.y + a.z + a.w;
  }
#pragma unroll
  for (int off = 32; off; off >>= 1) s += __shfl_xor(s, off);
  float mean = s * (1.f / 1024.f);
  float vs = 0.f;
#pragma unroll
  for (int ch = 0; ch < 4; ++ch) {
    float dx;
    dx = v[ch].x - mean; vs = fmaf(dx, dx, vs);
    dx = v[ch].y - mean; vs = fmaf(dx, dx, vs);
    dx = v[ch].z - mean; vs = fmaf(dx, dx, vs);
    dx = v[ch].w - mean; vs = fmaf(dx, dx, vs);
  }
#pragma unroll
  for (int off = 32; off; off >>= 1) vs += __shfl_xor(vs, off);
  float rstd = rsqrtf(vs * (1.f / 1024.f) + 1e-5f);
  float* y = out + (size_t)row * 1024;
#pragma unroll
  for (int ch = 0; ch < 4; ++ch) {
    int c = lane * 4 + ch * 256;
    float4 gg = *(const float4*)(g + c);
    float4 bv = *(const float4*)(bb + c);
    float4 o;
    o.x = fmaf((v[ch].x - mean) * rstd, gg.x, bv.x);
    o.y = fmaf((v[ch].y - mean) * rstd, gg.y, bv.y);
    o.z = fmaf((v[ch].z - mean) * rstd, gg.z, bv.z);
    o.w = fmaf((v[ch].w - mean) * rstd, gg.w, bv.w);
    *(float4*)(y + c) = o;
  }
}

// ---------------- fused perceiver attention core, one block per (batch,head) -
// P0 also does: mod_lat = LN(lat[b]; n2)*(1+scale_msa)+shift_msa
__global__ __launch_bounds__(256, 3) void k_attn(
    const float* __restrict__ normh,   // [32*257,1024]
    const float* __restrict__ lat,     // [32*8,1024] raw latents
    const float* __restrict__ wq,      // [1024,1024] this layer
    const float* __restrict__ wkv,     // [1024,2048] this layer
    const float* __restrict__ n1g, const float* __restrict__ n1b,
    const float* __restrict__ n2g, const float* __restrict__ n2b,
    const float* __restrict__ ada,     // [32,4096] this layer
    float* __restrict__ attn_out)      // [256,1024]
{
  int wg = blockIdx.x;
  int lg = (wg & 7) * 64 + (wg >> 3);  // XCD swizzle: 4 batches x 16 heads/XCD
  int b = lg >> 4, h = lg & 15;
  int t = threadIdx.x;

  __shared__ float ut[8][1024];      // mod_lat -> Ug -> T'
  __shared__ float qh[8][64];
  __shared__ float kl[8][64];
  __shared__ float vl[8][64];
  __shared__ float spT[280][8];      // scores/P, transposed [n][l]
  __shared__ float ubpart[16][8];
  __shared__ float ubs[8];
  __shared__ float rsxs[8];

  // P0: mod_lat = LN(lat[b]; n2)*(1+scale_msa)+shift_msa -> ut
  {
    int r = t >> 5, e = t & 31;        // 8 rows x 32 threads
    const float* src = lat + ((size_t)b * 8 + r) * 1024;
    float4 v[8];
    float s = 0.f;
#pragma unroll
    for (int j = 0; j < 8; ++j) {
      v[j] = *(const float4*)(src + e * 4 + j * 128);
      s += v[j].x + v[j].y + v[j].z + v[j].w;
    }
#pragma unroll
    for (int off = 16; off; off >>= 1) s += __shfl_xor(s, off, 32);
    float mean = s * (1.f / 1024.f);
    float vs = 0.f;
#pragma unroll
    for (int j = 0; j < 8; ++j) {
      float dx;
      dx = v[j].x - mean; vs = fmaf(dx, dx, vs);
      dx = v[j].y - mean; vs = fmaf(dx, dx, vs);
      dx = v[j].z - mean; vs = fmaf(dx, dx, vs);
      dx = v[j].w - mean; vs = fmaf(dx, dx, vs);
    }
#pragma unroll
    for (int off = 16; off; off >>= 1) vs += __shfl_xor(vs, off, 32);
    float rstd = rsqrtf(vs * (1.f / 1024.f) + 1e-5f);
    const float* ab = ada + (size_t)b * 4096;
#pragma unroll
    for (int j = 0; j < 8; ++j) {
      int c = e * 4 + j * 128;
      float4 gg = *(const float4*)(n2g + c);
      float4 bv = *(const float4*)(n2b + c);
      float4 sc = *(const float4*)(ab + 1024 + c);   // scale_msa
      float4 sh = *(const float4*)(ab + c);          // shift_msa
      float4 o;
      o.x = fmaf((v[j].x - mean) * rstd, gg.x, bv.x);
      o.y = fmaf((v[j].y - mean) * rstd, gg.y, bv.y);
      o.z = fmaf((v[j].z - mean) * rstd, gg.z, bv.z);
      o.w = fmaf((v[j].w - mean) * rstd, gg.w, bv.w);
      o.x = fmaf(o.x, 1.f + sc.x, sh.x);
      o.y = fmaf(o.y, 1.f + sc.y, sh.y);
      o.z = fmaf(o.z, 1.f + sc.z, sh.z);
      o.w = fmaf(o.w, 1.f + sc.w, sh.w);
      *(float4*)(&ut[r][c]) = o;
    }
  }
  __syncthreads();

  // P1: q' = (mod_lat @ wq_h)/8 ; klat = mod_lat @ Wk_h ; vlat = mod_lat @ Wv_h
  {
    int d = t & 63, lA = t >> 6, lB = lA + 4;
    const float* wqp = wq + h * 64 + d;
    const float* wkp = wkv + h * 64 + d;
    const float* wvp = wkv + 1024 + h * 64 + d;
    float qa = 0, qb = 0, ka = 0, kb = 0, va = 0, vb = 0;
#pragma unroll 4
    for (int c = 0; c < 1024; ++c) {
      float ma = ut[lA][c], mb = ut[lB][c];
      float w1 = wqp[(size_t)c * 1024];
      float w2 = wkp[(size_t)c * 2048];
      float w3 = wvp[(size_t)c * 2048];
      qa = fmaf(ma, w1, qa); qb = fmaf(mb, w1, qb);
      ka = fmaf(ma, w2, ka); kb = fmaf(mb, w2, kb);
      va = fmaf(ma, w3, va); vb = fmaf(mb, w3, vb);
    }
    qh[lA][d] = qa * 0.125f; qh[lB][d] = qb * 0.125f;   // fold 1/sqrt(64)
    kl[lA][d] = ka; kl[lB][d] = kb;
    vl[lA][d] = va; vl[lB][d] = vb;
  }
  __syncthreads();

  // P1b: latent-row scores S_lat[l][j] = q'[l] . klat[j]
  if (t < 64) {
    int l = t >> 3, j = t & 7;
    float s = 0;
#pragma unroll
    for (int d = 0; d < 64; ++d) s = fmaf(qh[l][d], kl[j][d], s);
    spT[257 + j][l] = s;
  }

  // P2: U[l][c] = q'[l] . Wk[c, h*64..]; store Ug = U*g1; ub[l] += U*b1
  {
    int g = t >> 4, e = t & 15;
    float uba = 0.f;
    for (int it = 0; it < 64; ++it) {
      int c = g + (it << 4);
      float4 w4 = *(const float4*)(wkv + (size_t)c * 2048 + h * 64 + e * 4);
      float pl[8];
#pragma unroll
      for (int l = 0; l < 8; ++l) {
        float4 q4 = *(const float4*)(&qh[l][e * 4]);
        pl[l] = q4.x * w4.x + q4.y * w4.y + q4.z * w4.z + q4.w * w4.w;
      }
#pragma unroll
      for (int off = 1; off < 16; off <<= 1) {
#pragma unroll
        for (int l = 0; l < 8; ++l) pl[l] += __shfl_xor(pl[l], off, 16);
      }
      if (e < 8) {
        ut[e][c] = pl[e] * n1g[c];
        uba = fmaf(pl[e], n1b[c], uba);
      }
    }
    if (e < 8) ubpart[g][e] = uba;
  }
  __syncthreads();
  if (t < 8) {
    float s = 0;
#pragma unroll
    for (int g2 = 0; g2 < 16; ++g2) s += ubpart[g2][t];
    ubs[t] = s;
  }
  __syncthreads();

  // P3: x-row scores S[l][n] = Ug[l] . normh[b,n] + ub[l], n in [0,257)
  {
    int g = t >> 4, e = t & 15;
#pragma unroll 1
    for (int it = 0; it < 4; ++it) {
      int n0 = (g + (it << 4)) << 2;        // full 4-wide tiles, n0 <= 252
      float acc[8][4];
#pragma unroll
      for (int l = 0; l < 8; ++l)
#pragma unroll
        for (int nn = 0; nn < 4; ++nn) acc[l][nn] = 0.f;
      const float* nh0 = normh + ((size_t)b * 257 + n0) * 1024 + e * 4;
      for (int ch = 0; ch < 16; ++ch) {
        float4 u4[8];
#pragma unroll
        for (int l = 0; l < 8; ++l)
          u4[l] = *(const float4*)(&ut[l][e * 4 + ch * 64]);
#pragma unroll
        for (int nn = 0; nn < 4; ++nn) {
          float4 v = *(const float4*)(nh0 + (size_t)nn * 1024 + ch * 64);
#pragma unroll
          for (int l = 0; l < 8; ++l)
            acc[l][nn] += u4[l].x * v.x + u4[l].y * v.y + u4[l].z * v.z + u4[l].w * v.w;
        }
      }
#pragma unroll
      for (int off = 1; off < 16; off <<= 1)
#pragma unroll
        for (int l = 0; l < 8; ++l)
#pragma unroll
          for (int nn = 0; nn < 4; ++nn)
            acc[l][nn] += __shfl_xor(acc[l][nn], off, 16);
      if (e < 8) {
#pragma unroll
        for (int nn = 0; nn < 4; ++nn)
          spT[n0 + nn][e] = acc[e][nn] + ubs[e];
      }
    }
    if (g == 0) {                            // tail row n = 256
      float acc[8];
#pragma unroll
      for (int l = 0; l < 8; ++l) acc[l] = 0.f;
      const float* nh0 = normh + ((size_t)b * 257 + 256) * 1024 + e * 4;
      for (int ch = 0; ch < 16; ++ch) {
        float4 v = *(const float4*)(nh0 + ch * 64);
#pragma unroll
        for (int l = 0; l < 8; ++l) {
          float4 u4 = *(const float4*)(&ut[l][e * 4 + ch * 64]);
          acc[l] += u4.x * v.x + u4.y * v.y + u4.z * v.z + u4.w * v.w;
        }
      }
#pragma unroll
      for (int off = 1; off < 16; off <<= 1)
#pragma unroll
        for (int l = 0; l < 8; ++l) acc[l] += __shfl_xor(acc[l], off, 16);
      if (e < 8) spT[256][e] = acc[e] + ubs[e];
    }
  }
  __syncthreads();

  // P4: softmax over 265 per row; rsx = sum of P over x-rows (n<257)
  {
    int w = t >> 6, lane = t & 63;
#pragma unroll
    for (int rr = 0; rr < 2; ++rr) {
      int r = w + rr * 4;
      float vb[5];
      float m = -1e30f;
#pragma unroll
      for (int k = 0; k < 5; ++k) {
        int n = lane + (k << 6);
        float v2 = (n < 265) ? spT[n][r] : -1e30f;
        vb[k] = v2;
        m = fmaxf(m, v2);
      }
#pragma unroll
      for (int off = 32; off; off >>= 1) m = fmaxf(m, __shfl_xor(m, off));
      float se = 0.f, sx = 0.f;
#pragma unroll
      for (int k = 0; k < 5; ++k) {
        int n = lane + (k << 6);
        float ev = 0.f;
        if (n < 265) {
          ev = expf(vb[k] - m);
          se += ev;
          if (n < 257) sx += ev;
        }
        vb[k] = ev;
      }
#pragma unroll
      for (int off = 32; off; off >>= 1) { se += __shfl_xor(se, off); sx += __shfl_xor(sx, off); }
      float inv = 1.f / se;
#pragma unroll
      for (int k = 0; k < 5; ++k) {
        int n = lane + (k << 6);
        if (n < 265) spT[n][r] = vb[k] * inv;
      }
      if (lane == 0) rsxs[r] = sx * inv;
    }
  }
  __syncthreads();

  // P5: T0 = Px @ normh[b]; T' = g1*T0 + b1*rsx  -> store into ut
  {
    float4 acc[8];
#pragma unroll
    for (int l = 0; l < 8; ++l) acc[l] = make_float4(0.f, 0.f, 0.f, 0.f);
    const float* nh = normh + (size_t)b * 257 * 1024 + t * 4;
    for (int n = 0; n < 257; ++n) {
      float4 v = *(const float4*)(nh + (size_t)n * 1024);
      float4 pA = *(const float4*)(&spT[n][0]);
      float4 pB = *(const float4*)(&spT[n][4]);
#define ACC1(i, p)                                   \
      acc[i].x = fmaf(p, v.x, acc[i].x);             \
      acc[i].y = fmaf(p, v.y, acc[i].y);             \
      acc[i].z = fmaf(p, v.z, acc[i].z);             \
      acc[i].w = fmaf(p, v.w, acc[i].w)
      ACC1(0, pA.x); ACC1(1, pA.y); ACC1(2, pA.z); ACC1(3, pA.w);
      ACC1(4, pB.x); ACC1(5, pB.y); ACC1(6, pB.z); ACC1(7, pB.w);
#undef ACC1
    }
    float4 g4 = *(const float4*)(n1g + t * 4);
    float4 b4 = *(const float4*)(n1b + t * 4);
#pragma unroll
    for (int l = 0; l < 8; ++l) {
      float r = rsxs[l];
      acc[l].x = fmaf(acc[l].x, g4.x, b4.x * r);
      acc[l].y = fmaf(acc[l].y, g4.y, b4.y * r);
      acc[l].z = fmaf(acc[l].z, g4.z, b4.z * r);
      acc[l].w = fmaf(acc[l].w, g4.w, b4.w * r);
      *(float4*)(&ut[l][t * 4]) = acc[l];
    }
  }
  __syncthreads();

  // P6: out[l][d] = T'[l] . Wv[:,h*64+d]  +  sum_j P[l,257+j]*vlat[j][d]
  {
    int d = t & 63, lA = t >> 6, lB = lA + 4;
    const float* wvp = wkv + 1024 + h * 64 + d;
    float oa = 0.f, ob = 0.f;
#pragma unroll 4
    for (int c = 0; c < 1024; ++c) {
      float w = wvp[(size_t)c * 2048];
      oa = fmaf(ut[lA][c], w, oa);
      ob = fmaf(ut[lB][c], w, ob);
    }
#pragma unroll
    for (int j = 0; j < 8; ++j) {
      float w = vl[j][d];
      oa = fmaf(spT[257 + j][lA], w, oa);
      ob = fmaf(spT[257 + j][lB], w, ob);
    }
    attn_out[(size_t)(b * 8 + lA) * 1024 + h * 64 + d] = oa;
    attn_out[(size_t)(b * 8 + lB) * 1024 + h * 64 + d] = ob;
  }
}

// -----------------------------------------------------------------------------
extern "C" void kernel_launch(void* const* d_in, const int* in_sizes, int n_in,
                              void* d_out, int out_size, void* d_ws, size_t ws_size,
                              hipStream_t stream)
{
  const float* x    = (const float*)d_in[0];
  const int*   ts   = (const int*)d_in[1];
  const float* lat0 = (const float*)d_in[2];
  const float* piw  = (const float*)d_in[3];
  const float* pib  = (const float*)d_in[4];
  const float* t1w  = (const float*)d_in[5];
  const float* t1b  = (const float*)d_in[6];
  const float* t2w  = (const float*)d_in[7];
  const float* t2b  = (const float*)d_in[8];
  const float* n1g  = (const float*)d_in[9];
  const float* n1b  = (const float*)d_in[10];
  const float* n2g  = (const float*)d_in[11];
  const float* n2b  = (const float*)d_in[12];
  const float* wq   = (const float*)d_in[13];
  const float* wkv  = (const float*)d_in[14];
  const float* wo   = (const float*)d_in[15];
  const float* ffg  = (const float*)d_in[16];
  const float* ffb  = (const float*)d_in[17];
  const float* ffw1 = (const float*)d_in[18];
  const float* ffw2 = (const float*)d_in[19];
  const float* adaw = (const float*)d_in[20];
  const float* adab = (const float*)d_in[21];
  const float* poW  = (const float*)d_in[22];
  const float* poB  = (const float*)d_in[23];
  const float* outg = (const float*)d_in[24];
  const float* outb = (const float*)d_in[25];

  float* ws    = (float*)d_ws;
  float* temb  = ws;                      // 32768
  float* st    = temb + 32768;            // 32768
  float* h     = st + 32768;              // 8421376 (normh computed in-place)
  float* ada   = h + 8421376;             // 1048576 (8 layers x 32 x 4096)
  float* lat   = ada + 1048576;           // 262144
  float* yb    = lat + 262144;            // 262144
  float* zb    = yb + 262144;             // 1048576
  float* attn  = zb + 1048576;            // 262144
  float* pp    = attn + 262144;           // 1048576 (split-K partials, z<=4)
  // total 12,419,072 floats = 49.7 MB

  // temb + silu(temb)
  k_temb<<<32, 256, 0, stream>>>(ts, t1w, t1b, t2w, t2b, temb, st);
  // h = x @ proj_in_w + b + temb[b]   (128x64 tiles)
  k_gemm<8><<<dim3(65, 16, 1), 256, 0, stream>>>(
      x, 0, 768, piw, 0, h, 0, pib, 0, nullptr, temb, 8224, 1024, 768, 2);
  // norm_h in-place (layer-invariant part of xn)
  k_ln<<<2056, 256, 0, stream>>>(h, h, nullptr, nullptr);
  float* normh = h;
  // lat = broadcast latents
  k_latinit<<<256, 256, 0, stream>>>(lat0, lat);
  // ada for all 8 layers at once: silu(temb) @ ada_w[i] + ada_b[i]
  k_gemm<2><<<dim3(1, 64, 8), 256, 0, stream>>>(
      st, 0, 1024, adaw, 4194304L, ada, 131072L, adab, 4096, nullptr, nullptr,
      32, 4096, 1024, 0);

  for (int i = 0; i < 8; ++i) {
    const float* wq_i  = wq + (size_t)i * 1048576;
    const float* wkv_i = wkv + (size_t)i * 2097152;
    const float* wo_i  = wo + (size_t)i * 1048576;
    float* ada_i = ada + (size_t)i * 131072;
    // fused attention core (includes LN(lat;n2)+adaLN modulation)
    k_attn<<<512, 256, 0, stream>>>(normh, lat, wq_i, wkv_i,
                                    n1g + i * 1024, n1b + i * 1024,
                                    n2g + i * 1024, n2b + i * 1024,
                                    ada_i, attn);
    // attn @ wo  (split-K z=2, Kc=512) -> pp   [SWAP grid: cols x rows]
    k_gemm<2, true><<<dim3(16, 8, 2), 256, 0, stream>>>(
        attn, 512, 1024, wo_i, 524288L, pp, 262144L, nullptr, 0, nullptr,
        nullptr, 256, 1024, 512, 0);
    // lat += sum(pp); yb = LN(lat;ff)*(1+scale_mlp)+shift_mlp
    k_redln<<<64, 256, 0, stream>>>(pp, 2, 65536, lat, yb,
                                    ffg + i * 1024, ffb + i * 1024,
                                    ada_i, 2048, 3072);
    // z = gelu(yb @ ff_w1)   [SWAP grid]
    k_gemm<2, true><<<dim3(64, 8, 1), 256, 0, stream>>>(
        yb, 0, 1024, ffw1 + (size_t)i * 4194304, 0, zb, 0, nullptr, 0, nullptr,
        nullptr, 256, 4096, 1024, 1);
    // lat += z @ ff_w2   (split-K z=4, Kc=1024)   [SWAP grid]
    k_gemm<2, true><<<dim3(16, 8, 4), 256, 0, stream>>>(
        zb, 1024, 4096, ffw2 + (size_t)i * 4194304, 1048576L, pp, 262144L,
        nullptr, 0, nullptr, nullptr, 256, 1024, 1024, 0);
    k_reduce<<<256, 256, 0, stream>>>(pp, 65536, 4, lat, lat, 65536);
  }
  // proj_out (split-K z=2) then fused reduce+bias+LN -> d_out
  k_gemm<2, true><<<dim3(16, 8, 2), 256, 0, stream>>>(
      lat, 512, 1024, poW, 524288L, pp, 262144L, nullptr, 0, nullptr,
      nullptr, 256, 1024, 512, 0);
  k_redout<<<64, 256, 0, stream>>>(pp, 2, 65536, poB, outg, outb,
                                   (float*)d_out);
}